// Round 13
// baseline (1919.247 us; speedup 1.0000x reference)
//
#include <hip/hip_runtime.h>
#include <cstdint>
#include <cstddef>

#define NPTS 8192
#define MCTR 2048
#define BATCH 4
#define KNB 32

typedef float v2f __attribute__((ext_vector_type(2)));

// ---- u32 wave max via DPP (identity 0, values >= 0), foldable to v_max_u32_dpp.
// row_shr:N pushes data to HIGHER lanes; max accumulates in lane 63. ----
__device__ __forceinline__ unsigned wave_max_u32(unsigned x) {
  unsigned t;
  t = (unsigned)__builtin_amdgcn_update_dpp(0, (int)x, 0x111, 0xf, 0xf, false);
  x = x > t ? x : t;
  t = (unsigned)__builtin_amdgcn_update_dpp(0, (int)x, 0x112, 0xf, 0xf, false);
  x = x > t ? x : t;
  t = (unsigned)__builtin_amdgcn_update_dpp(0, (int)x, 0x114, 0xf, 0xf, false);
  x = x > t ? x : t;
  t = (unsigned)__builtin_amdgcn_update_dpp(0, (int)x, 0x118, 0xf, 0xf, false);
  x = x > t ? x : t;
  t = (unsigned)__builtin_amdgcn_update_dpp(0, (int)x, 0x142, 0xa, 0xf, false);
  x = x > t ? x : t;
  t = (unsigned)__builtin_amdgcn_update_dpp(0, (int)x, 0x143, 0xc, 0xf, false);
  x = x > t ? x : t;
  return (unsigned)__builtin_amdgcn_readlane((int)x, 63);
}

// ---- u32 max over lanes 0..7 (accumulates in lane 7), broadcast ----
__device__ __forceinline__ unsigned oct_max_u32(unsigned x) {
  unsigned t;
  t = (unsigned)__builtin_amdgcn_update_dpp(0, (int)x, 0x114, 0xf, 0xf, false);
  x = x > t ? x : t;
  t = (unsigned)__builtin_amdgcn_update_dpp(0, (int)x, 0x112, 0xf, 0xf, false);
  x = x > t ? x : t;
  t = (unsigned)__builtin_amdgcn_update_dpp(0, (int)x, 0x111, 0xf, 0xf, false);
  x = x > t ? x : t;
  return (unsigned)__builtin_amdgcn_readlane((int)x, 7);
}

// ---------- feature transpose (B,32,N) -> (B,N,32) ----------
__global__ __launch_bounds__(256) void featT_kernel(const float* __restrict__ feats,
                                                    float* __restrict__ featT) {
  const int bn = blockIdx.x;
  const int b = bn >> 8;
  const int n0 = (bn & 255) * 32;
  __shared__ float tile[32][33];
  const int tx = threadIdx.x & 31, ty = threadIdx.x >> 5;
  const float* src = feats + (size_t)b * 32 * NPTS;
#pragma unroll
  for (int s = 0; s < 4; ++s) {
    int f = ty + 8 * s;
    tile[f][tx] = src[(size_t)f * NPTS + n0 + tx];
  }
  __syncthreads();
  float* dst = featT + ((size_t)b * NPTS + n0) * 32;
#pragma unroll
  for (int s = 0; s < 4; ++s) {
    int n = ty + 8 * s;
    dst[n * 32 + tx] = tile[tx][n];
  }
}

// ---------- weight transpose ----------
__global__ __launch_bounds__(256) void prep_kernel(const float* __restrict__ W1,
                                                   const float* __restrict__ W2,
                                                   const float* __restrict__ W3,
                                                   float* __restrict__ Wt) {
  const int t = blockIdx.x * 256 + threadIdx.x;
  if (t < 2240) { int c = t >> 6, o = t & 63;  Wt[t] = W1[o * 35 + c]; }
  if (t < 4096) { int c = t >> 6, o = t & 63;  Wt[2240 + t] = W2[o * 64 + c]; }
  if (t < 8192) { int c = t >> 7, o = t & 127; Wt[6336 + t] = W3[o * 64 + c]; }
}

// ---------- counting sort by x-bucket (512 buckets), one block per batch ----------
__global__ __launch_bounds__(512) void xsort_kernel(const float* __restrict__ coords,
                                                    float* __restrict__ sX,
                                                    float* __restrict__ sY,
                                                    float* __restrict__ sZ,
                                                    int* __restrict__ sOrig) {
  const int b = blockIdx.x;
  const int tid = threadIdx.x;
  const float* C = coords + (size_t)b * 3 * NPTS;
  __shared__ int h[512];
  __shared__ int cur[512];
  h[tid] = 0;
  __syncthreads();
  int bk[16];
#pragma unroll
  for (int j = 0; j < 16; ++j) {
    int i = tid + j * 512;
    float x = C[i];
    int k = (int)(x * 512.0f);
    k = k < 0 ? 0 : (k > 511 ? 511 : k);
    bk[j] = k;
    atomicAdd(&h[k], 1);
  }
  __syncthreads();
  const int cnt = h[tid];
  for (int s = 1; s < 512; s <<= 1) {
    int v = (tid >= s) ? h[tid - s] : 0;
    __syncthreads();
    h[tid] += v;
    __syncthreads();
  }
  cur[tid] = h[tid] - cnt;
  __syncthreads();
  float* dX = sX + (size_t)b * NPTS;
  float* dY = sY + (size_t)b * NPTS;
  float* dZ = sZ + (size_t)b * NPTS;
  int* dO = sOrig + (size_t)b * NPTS;
#pragma unroll
  for (int j = 0; j < 16; ++j) {
    int i = tid + j * 512;
    int pos = atomicAdd(&cur[bk[j]], 1);
    dX[pos] = C[i];
    dY[pos] = C[NPTS + i];
    dZ[pos] = C[2 * NPTS + i];
    dO[pos] = i;
  }
}

// ---------- furthest point sampling ----------
// Blocked ownership + exact bbox cull + packed hot loop (fp contract off ==
// bit-exact vs reference). Reduce = phase A (u32 DPP max of dist bits) + ballot
// fast-path tie-break (exact DPP fallback on rare multi-achiever). Candidate
// centroids travel through scand[] next to keys: post-barrier the winner's xyz
// comes from readlane (no dependent LDS read after the reduce).
__global__ __launch_bounds__(512) void fps_kernel(const float* __restrict__ sX,
                                                  const float* __restrict__ sY,
                                                  const float* __restrict__ sZ,
                                                  const int* __restrict__ sOrig,
                                                  int* __restrict__ cidx,
                                                  float* __restrict__ centers) {
  const int b = blockIdx.x;
  const int tid = threadIdx.x;
  const int wave = tid >> 6, lane = tid & 63;
  __shared__ __align__(16) float4 lC4[NPTS];  // 128 KiB
  __shared__ __align__(16) unsigned long long skey[2][8];
  __shared__ __align__(16) float4 scand[2][8];
  __shared__ int s_slot0;
  const float* gX = sX + (size_t)b * NPTS;
  const float* gY = sY + (size_t)b * NPTS;
  const float* gZ = sZ + (size_t)b * NPTS;
  const int* gO = sOrig + (size_t)b * NPTS;
  for (int i = tid; i < NPTS; i += 512) {
    float4 v;
    v.x = gX[i]; v.y = gY[i]; v.z = gZ[i]; v.w = 0.0f;
    lC4[i] = v;
  }
  const int base = tid * 16;
  int og[16];
#pragma unroll
  for (int j = 0; j < 16; ++j) {
    og[j] = gO[base + j];
    if (og[j] == 0) s_slot0 = base + j;  // exactly one thread writes
  }
  __syncthreads();
  v2f px[8], py[8], pz[8], dd[8];
#pragma unroll
  for (int p = 0; p < 8; ++p) {
    float4 c0 = lC4[base + 2 * p];
    float4 c1 = lC4[base + 2 * p + 1];
    px[p].x = c0.x; px[p].y = c1.x;
    py[p].x = c0.y; py[p].y = c1.y;
    pz[p].x = c0.z; pz[p].y = c1.z;
    dd[p].x = __builtin_inff(); dd[p].y = __builtin_inff();
  }
  // exact bbox of owned points
  v2f xl = px[0], xh = px[0], yl = py[0], yh = py[0], zl = pz[0], zh = pz[0];
#pragma unroll
  for (int p = 1; p < 8; ++p) {
    xl = __builtin_elementwise_min(xl, px[p]); xh = __builtin_elementwise_max(xh, px[p]);
    yl = __builtin_elementwise_min(yl, py[p]); yh = __builtin_elementwise_max(yh, py[p]);
    zl = __builtin_elementwise_min(zl, pz[p]); zh = __builtin_elementwise_max(zh, pz[p]);
  }
  const float xlo = fminf(xl.x, xl.y), xhi = fmaxf(xh.x, xh.y);
  const float ylo = fminf(yl.x, yl.y), yhi = fmaxf(yh.x, yh.y);
  const float zlo = fminf(zl.x, zl.y), zhi = fmaxf(zh.x, zh.y);
  float cmax = __builtin_inff();
  int amin17 = (og[0] << 4) | 0;
#pragma unroll
  for (int j = 1; j < 16; ++j) amin17 = min(amin17, (og[j] << 4) | j);
  const int slot0 = s_slot0;
  float4 cc = lC4[slot0];
  float cx = cc.x, cy = cc.y, cz = cc.z;
  unsigned long long wkey = 0;
  float4 candw = cc;  // lane==wave's cached copy of this wave's candidate xyz
  unsigned long long kreg[4];
  if (tid == 0)  // m=0: initial point, orig 0 (dist bits unused by writeback)
    kreg[0] = ((unsigned long long)(unsigned)8191 << 13) | (unsigned)slot0;
  int buf = 0;
  for (int it = 0; it < MCTR; ++it) {
    float dxm = fmaxf(fmaxf(xlo - cx, cx - xhi), 0.0f);
    float dym = fmaxf(fmaxf(ylo - cy, cy - yhi), 0.0f);
    float dzm = fmaxf(fmaxf(zlo - cz, cz - zhi), 0.0f);
    float lb = dxm * dxm + dym * dym + dzm * dzm;
    bool active = !(lb * 0.999999f >= cmax);  // margin makes skip provably exact
    unsigned long long mk = __ballot(active ? 1 : 0);
    if (mk != 0ull) {
      if (active) {
        v2f vcx, vcy, vcz;
        vcx.x = cx; vcx.y = cx;
        vcy.x = cy; vcy.y = cy;
        vcz.x = cz; vcz.y = cz;
        {
#pragma clang fp contract(off)
          // EXACT reference order per half: (dx*dx + dy*dy) + dz*dz, rn each
          // step, no FMA (contract off). Packed == scalar bit-exact.
#pragma unroll
          for (int p = 0; p < 8; ++p) {
            v2f dx = px[p] - vcx;
            v2f dy = py[p] - vcy;
            v2f dz = pz[p] - vcz;
            v2f d = (dx * dx + dy * dy) + dz * dz;
            dd[p] = __builtin_elementwise_min(dd[p], d);
          }
        }
        v2f m01 = __builtin_elementwise_max(dd[0], dd[1]);
        v2f m23 = __builtin_elementwise_max(dd[2], dd[3]);
        v2f m45 = __builtin_elementwise_max(dd[4], dd[5]);
        v2f m67 = __builtin_elementwise_max(dd[6], dd[7]);
        v2f m03 = __builtin_elementwise_max(m01, m23);
        v2f m47 = __builtin_elementwise_max(m45, m67);
        v2f mm = __builtin_elementwise_max(m03, m47);
        cmax = fmaxf(mm.x, mm.y);
        // min ORIGINAL idx among achievers — depth-4 tree
        int c0, c1, c2, c3, c4, c5, c6, c7;
        c0 = min(dd[0].x == cmax ? ((og[0] << 4) | 0) : 0x7fffffff,
                 dd[0].y == cmax ? ((og[1] << 4) | 1) : 0x7fffffff);
        c1 = min(dd[1].x == cmax ? ((og[2] << 4) | 2) : 0x7fffffff,
                 dd[1].y == cmax ? ((og[3] << 4) | 3) : 0x7fffffff);
        c2 = min(dd[2].x == cmax ? ((og[4] << 4) | 4) : 0x7fffffff,
                 dd[2].y == cmax ? ((og[5] << 4) | 5) : 0x7fffffff);
        c3 = min(dd[3].x == cmax ? ((og[6] << 4) | 6) : 0x7fffffff,
                 dd[3].y == cmax ? ((og[7] << 4) | 7) : 0x7fffffff);
        c4 = min(dd[4].x == cmax ? ((og[8] << 4) | 8) : 0x7fffffff,
                 dd[4].y == cmax ? ((og[9] << 4) | 9) : 0x7fffffff);
        c5 = min(dd[5].x == cmax ? ((og[10] << 4) | 10) : 0x7fffffff,
                 dd[5].y == cmax ? ((og[11] << 4) | 11) : 0x7fffffff);
        c6 = min(dd[6].x == cmax ? ((og[12] << 4) | 12) : 0x7fffffff,
                 dd[6].y == cmax ? ((og[13] << 4) | 13) : 0x7fffffff);
        c7 = min(dd[7].x == cmax ? ((og[14] << 4) | 14) : 0x7fffffff,
                 dd[7].y == cmax ? ((og[15] << 4) | 15) : 0x7fffffff);
        amin17 = min(min(min(c0, c1), min(c2, c3)), min(min(c4, c5), min(c6, c7)));
      }
      const unsigned mydist = __float_as_uint(cmax);
      const unsigned mytail =
          ((unsigned)(8191 - (amin17 >> 4)) << 13) | (unsigned)(base + (amin17 & 15));
      // candidate xyz read issued BEFORE the reduce (address independent of it);
      // overlaps the DPP chain. Valid for cached (inactive) lanes too.
      const float4 myc = lC4[base + (amin17 & 15)];
      const unsigned gwd = wave_max_u32(mydist);  // phase A: dist
      const unsigned long long mkA = __ballot(mydist == gwd);
      unsigned gwt;
      if (__popcll(mkA) == 1) {  // unique achiever: tail via readlane (common)
        gwt = (unsigned)__builtin_amdgcn_readlane((int)mytail,
                                                  (int)__builtin_ctzll(mkA));
      } else {  // exact fallback: max tail among achievers (min ORIGINAL idx)
        gwt = wave_max_u32(mydist == gwd ? mytail : 0u);
      }
      wkey = ((unsigned long long)gwd << 32) | gwt;
      if (mytail == gwt) {  // unique lane: tails are distinct
        skey[buf][wave] = wkey;
        scand[buf][wave] = myc;
      }
    } else {
      if (lane == wave) {  // holds this wave's scand from post-barrier read
        skey[buf][wave] = wkey;
        scand[buf][wave] = candw;
      }
    }
    __syncthreads();
    // post-barrier: key + candidate-xyz multicast reads in parallel
    const unsigned long long kc = skey[buf][lane & 7];
    const float4 cand = scand[buf][lane & 7];
    const unsigned kd = (unsigned)(kc >> 32), kt = (unsigned)kc;
    const unsigned gd = oct_max_u32(kd);
    const unsigned long long mk2 = __ballot(kd == gd);
    unsigned gt;
    if (__popcll(mk2) == 8) {  // one achiever wave (8 replicas)
      gt = (unsigned)__builtin_amdgcn_readlane((int)kt, (int)__builtin_ctzll(mk2));
    } else {  // exact fallback
      gt = oct_max_u32(kd == gd ? kt : 0u);
    }
    const unsigned long long gk = ((unsigned long long)gd << 32) | gt;
    if (((it + 1) >> 2) == tid) kreg[(it + 1) & 3] = gk;  // winner for m=it+1
    const int w = (int)((gt & 0x1fffu) >> 10);  // winning wave (slot>>4=tid,>>6=wave)
    cx = __int_as_float(__builtin_amdgcn_readlane(__float_as_int(cand.x), w));
    cy = __int_as_float(__builtin_amdgcn_readlane(__float_as_int(cand.y), w));
    cz = __int_as_float(__builtin_amdgcn_readlane(__float_as_int(cand.z), w));
    candw = cand;
    buf ^= 1;
  }
  // coalesced writeback: thread t owns centers m = 4t..4t+3
#pragma unroll
  for (int r = 0; r < 4; ++r) {
    unsigned long long k = kreg[r];
    int orig = 8191 - (int)((k >> 13) & 0x1fff);
    int sl = (int)(k & 0x1fff);
    int m = 4 * tid + r;
    float4 c = lC4[sl];
    cidx[b * MCTR + m] = orig;
    centers[(size_t)b * 3 * MCTR + m] = c.x;
    centers[(size_t)b * 3 * MCTR + MCTR + m] = c.y;
    centers[(size_t)b * 3 * MCTR + 2 * MCTR + m] = c.z;
  }
}

// ---------- ball query: one wave per center, software-pipelined loads ----------
__global__ __launch_bounds__(256) void ballq_kernel(const float* __restrict__ coords,
                                                    const int* __restrict__ cidx,
                                                    int* __restrict__ nbidx) {
  const int wib = threadIdx.x >> 6;
  const int gw = blockIdx.x * 4 + wib;
  const int lane = threadIdx.x & 63;
  const int b = gw >> 11;
  const float* C = coords + (size_t)b * 3 * NPTS;
  const int ci = cidx[gw];
  const float cx = C[ci], cy = C[NPTS + ci], cz = C[2 * NPTS + ci];
  // python double 0.2*0.2 demoted to f32 == 0x3D23D70A (NOT 0.2f*0.2f!)
  const float R2 = (float)(0.2 * 0.2);
  __shared__ int sbuf[4][32];
  int* buf = sbuf[wib];
  int count = 0;
  float xx = C[lane], yy = C[NPTS + lane], zz = C[2 * NPTS + lane];
  for (int base = 0; base < NPTS && count < 32; base += 64) {
    float nx = 0.f, ny = 0.f, nz = 0.f;
    if (base + 64 < NPTS) {  // prefetch next round while this round resolves
      const int ni = base + 64 + lane;
      nx = C[ni]; ny = C[NPTS + ni]; nz = C[2 * NPTS + ni];
    }
    float dx = __fsub_rn(cx, xx);
    float dy = __fsub_rn(cy, yy);
    float dz = __fsub_rn(cz, zz);
    float d2 = __fadd_rn(__fadd_rn(__fmul_rn(dx, dx), __fmul_rn(dy, dy)), __fmul_rn(dz, dz));
    bool q = d2 < R2;
    unsigned long long mk = __ballot(q ? 1 : 0);
    int pos = count + (int)__popcll(mk & ((1ull << lane) - 1ull));
    if (q && pos < 32) buf[pos] = base + lane;
    count += (int)__popcll(mk);
    xx = nx; yy = ny; zz = nz;
  }
  __syncthreads();
  if (lane < 32) {
    int cnt = count < 32 ? count : 32;
    int first = (count > 0) ? buf[0] : 0;
    int v = (lane < cnt) ? buf[lane] : first;
    nbidx[(size_t)gw * KNB + lane] = v;
  }
}

// ---------- MLP with XOR-swizzled LDS ----------
__device__ __forceinline__ int SW(int ch, int col) {
  return 32 * ch + (col ^ ((((ch) >> 2) & 7) << 2));
}

__device__ __forceinline__ void layerT(const float* __restrict__ X,
                                       const float* __restrict__ W, int ldw, int cin,
                                       float4 bias, int og, int kg, float acc[4][8]) {
  const float bv[4] = {bias.x, bias.y, bias.z, bias.w};
#pragma unroll
  for (int oi = 0; oi < 4; ++oi)
#pragma unroll
    for (int ki = 0; ki < 8; ++ki) acc[oi][ki] = bv[oi];
#pragma unroll 4
  for (int c = 0; c < cin; ++c) {
    const float4 xa = *(const float4*)(X + SW(c, 8 * kg));
    const float4 xb = *(const float4*)(X + SW(c, 8 * kg + 4));
    float4 w = *(const float4*)(W + ldw * c + 4 * og);
    const float wv[4] = {w.x, w.y, w.z, w.w};
    const float xv[8] = {xa.x, xa.y, xa.z, xa.w, xb.x, xb.y, xb.z, xb.w};
#pragma unroll
    for (int oi = 0; oi < 4; ++oi)
#pragma unroll
      for (int ki = 0; ki < 8; ++ki)
        acc[oi][ki] = fmaf(wv[oi], xv[ki], acc[oi][ki]);
  }
}

__device__ __forceinline__ void storeT(float* __restrict__ dst, int og, int kg,
                                       const float acc[4][8]) {
#pragma unroll
  for (int oi = 0; oi < 4; ++oi) {
    float4 va, vb;
    va.x = fmaxf(acc[oi][0], 0.f); va.y = fmaxf(acc[oi][1], 0.f);
    va.z = fmaxf(acc[oi][2], 0.f); va.w = fmaxf(acc[oi][3], 0.f);
    vb.x = fmaxf(acc[oi][4], 0.f); vb.y = fmaxf(acc[oi][5], 0.f);
    vb.z = fmaxf(acc[oi][6], 0.f); vb.w = fmaxf(acc[oi][7], 0.f);
    const int r = 4 * og + oi;
    *(float4*)(dst + SW(r, 8 * kg)) = va;
    *(float4*)(dst + SW(r, 8 * kg + 4)) = vb;
  }
}

__global__ __launch_bounds__(64) void mlp_kernel(const float* __restrict__ coords,
                                                 const float* __restrict__ featT,
                                                 const float* __restrict__ Wt,
                                                 const float* __restrict__ b1,
                                                 const float* __restrict__ b2,
                                                 const float* __restrict__ b3,
                                                 const int* __restrict__ cidx,
                                                 const int* __restrict__ nbidx,
                                                 float* __restrict__ outT) {
  const int g = blockIdx.x;
  const int b = g >> 11;
  const int lane = threadIdx.x;
  const int og = lane & 15, kg = lane >> 4;
  __shared__ __align__(16) float A[64 * 32];
  __shared__ __align__(16) float Bf[64 * 32];
  const float* C = coords + (size_t)b * 3 * NPTS;
  const int ci = cidx[g];
  const float ccx = C[ci], ccy = C[NPTS + ci], ccz = C[2 * NPTS + ci];
  const int* nb = nbidx + (size_t)g * KNB;
  if (lane < 32) {
    const int n = nb[lane];
    A[SW(0, lane)] = C[n] - ccx;
    A[SW(1, lane)] = C[NPTS + n] - ccy;
    A[SW(2, lane)] = C[2 * NPTS + n] - ccz;
    const float4* f = (const float4*)(featT + ((size_t)b * NPTS + n) * 32);
#pragma unroll
    for (int q = 0; q < 4; ++q) {
      float4 v = f[q];
      A[SW(3 + 4 * q, lane)] = v.x;
      A[SW(4 + 4 * q, lane)] = v.y;
      A[SW(5 + 4 * q, lane)] = v.z;
      A[SW(6 + 4 * q, lane)] = v.w;
    }
  } else {
    const int k = lane - 32;
    const int n = nb[k];
    const float4* f = (const float4*)(featT + ((size_t)b * NPTS + n) * 32);
#pragma unroll
    for (int q = 4; q < 8; ++q) {
      float4 v = f[q];
      A[SW(3 + 4 * q, k)] = v.x;
      A[SW(4 + 4 * q, k)] = v.y;
      A[SW(5 + 4 * q, k)] = v.z;
      A[SW(6 + 4 * q, k)] = v.w;
    }
  }
  __syncthreads();
  float acc[4][8];
  layerT(A, Wt, 64, 35, *(const float4*)(b1 + 4 * og), og, kg, acc);
  storeT(Bf, og, kg, acc);
  __syncthreads();
  layerT(Bf, Wt + 2240, 64, 64, *(const float4*)(b2 + 4 * og), og, kg, acc);
  storeT(A, og, kg, acc);
  __syncthreads();
  float* outp = outT + (size_t)g * 128;
#pragma unroll 1
  for (int h = 0; h < 2; ++h) {
    layerT(A, Wt + 6336 + 64 * h, 128, 64, *(const float4*)(b3 + 64 * h + 4 * og), og,
           kg, acc);
    float4 res;
    float* rp = (float*)&res;
#pragma unroll
    for (int oi = 0; oi < 4; ++oi) {
      float m = 0.f;
#pragma unroll
      for (int ki = 0; ki < 8; ++ki) m = fmaxf(m, acc[oi][ki]);
      m = fmaxf(m, __shfl_xor(m, 16));
      m = fmaxf(m, __shfl_xor(m, 32));
      rp[oi] = m;
    }
    if (kg == 0) *(float4*)(outp + 64 * h + 4 * og) = res;
  }
}

// ---------- output transpose (B,M,128) -> (B,128,M) ----------
__global__ __launch_bounds__(256) void outT_kernel(const float* __restrict__ outT,
                                                   float* __restrict__ out) {
  const int bid = blockIdx.x;
  const int b = bid >> 8;
  const int r = bid & 255;
  const int o0 = (r >> 6) * 32;
  const int m0 = (r & 63) * 32;
  __shared__ float tile[32][33];
  const int tx = threadIdx.x & 31, ty = threadIdx.x >> 5;
  const float* src = outT + ((size_t)b * MCTR + m0) * 128;
#pragma unroll
  for (int s = 0; s < 4; ++s) {
    int m = ty + 8 * s;
    tile[m][tx] = src[(size_t)m * 128 + o0 + tx];
  }
  __syncthreads();
  float* dst = out + ((size_t)b * 128 + o0) * MCTR + m0;
#pragma unroll
  for (int s = 0; s < 4; ++s) {
    int o = ty + 8 * s;
    dst[(size_t)o * MCTR + tx] = tile[tx][o];
  }
}

extern "C" void kernel_launch(void* const* d_in, const int* in_sizes, int n_in,
                              void* d_out, int out_size, void* d_ws, size_t ws_size,
                              hipStream_t stream) {
  (void)in_sizes; (void)n_in; (void)out_size; (void)ws_size;
  const float* feats = (const float*)d_in[0];
  const float* coords = (const float*)d_in[1];
  const float* W1 = (const float*)d_in[2];
  const float* b1 = (const float*)d_in[3];
  const float* W2 = (const float*)d_in[4];
  const float* b2 = (const float*)d_in[5];
  const float* W3 = (const float*)d_in[6];
  const float* b3 = (const float*)d_in[7];
  float* out = (float*)d_out;
  float* centers = out + (size_t)BATCH * 128 * MCTR;

  float* ws_f = (float*)d_ws;
  float* featT = ws_f;                                     // 1,048,576 f
  float* Wt = ws_f + 1048576;                              //    14,528 f
  int* cidx = (int*)(ws_f + 1048576 + 14528);              //     8,192 i
  int* nbidx = (int*)(ws_f + 1048576 + 14528 + 8192);      //   262,144 i
  float* outTbuf = ws_f + 1048576 + 14528 + 8192 + 262144; // 1,048,576 f
  // sorted-coord arrays overlay outTbuf: dead before mlp_kernel writes it
  float* sX = outTbuf;                 // 32768 f
  float* sY = outTbuf + 32768;         // 32768 f
  float* sZ = outTbuf + 65536;         // 32768 f
  int* sOrig = (int*)(outTbuf + 98304);// 32768 i

  featT_kernel<<<1024, 256, 0, stream>>>(feats, featT);
  prep_kernel<<<32, 256, 0, stream>>>(W1, W2, W3, Wt);
  xsort_kernel<<<BATCH, 512, 0, stream>>>(coords, sX, sY, sZ, sOrig);
  fps_kernel<<<BATCH, 512, 0, stream>>>(sX, sY, sZ, sOrig, cidx, centers);
  ballq_kernel<<<2048, 256, 0, stream>>>(coords, cidx, nbidx);
  mlp_kernel<<<BATCH * MCTR, 64, 0, stream>>>(coords, featT, Wt, b1, b2, b3, cidx, nbidx, outTbuf);
  outT_kernel<<<1024, 256, 0, stream>>>(outTbuf, out);
}

// Round 14
// 1743.166 us; speedup vs baseline: 1.1010x; 1.1010x over previous
//
#include <hip/hip_runtime.h>
#include <cstdint>
#include <cstddef>

#define NPTS 8192
#define MCTR 2048
#define BATCH 4
#define KNB 32

typedef float v2f __attribute__((ext_vector_type(2)));

// ---- u32 wave max via DPP (identity 0, values >= 0), foldable to v_max_u32_dpp.
// row_shr:N pushes data to HIGHER lanes; max accumulates in lane 63. ----
__device__ __forceinline__ unsigned wave_max_u32(unsigned x) {
  unsigned t;
  t = (unsigned)__builtin_amdgcn_update_dpp(0, (int)x, 0x111, 0xf, 0xf, false);
  x = x > t ? x : t;
  t = (unsigned)__builtin_amdgcn_update_dpp(0, (int)x, 0x112, 0xf, 0xf, false);
  x = x > t ? x : t;
  t = (unsigned)__builtin_amdgcn_update_dpp(0, (int)x, 0x114, 0xf, 0xf, false);
  x = x > t ? x : t;
  t = (unsigned)__builtin_amdgcn_update_dpp(0, (int)x, 0x118, 0xf, 0xf, false);
  x = x > t ? x : t;
  t = (unsigned)__builtin_amdgcn_update_dpp(0, (int)x, 0x142, 0xa, 0xf, false);
  x = x > t ? x : t;
  t = (unsigned)__builtin_amdgcn_update_dpp(0, (int)x, 0x143, 0xc, 0xf, false);
  x = x > t ? x : t;
  return (unsigned)__builtin_amdgcn_readlane((int)x, 63);
}

// ---- u32 max over lanes 0..7 (accumulates in lane 7), broadcast ----
__device__ __forceinline__ unsigned oct_max_u32(unsigned x) {
  unsigned t;
  t = (unsigned)__builtin_amdgcn_update_dpp(0, (int)x, 0x114, 0xf, 0xf, false);
  x = x > t ? x : t;
  t = (unsigned)__builtin_amdgcn_update_dpp(0, (int)x, 0x112, 0xf, 0xf, false);
  x = x > t ? x : t;
  t = (unsigned)__builtin_amdgcn_update_dpp(0, (int)x, 0x111, 0xf, 0xf, false);
  x = x > t ? x : t;
  return (unsigned)__builtin_amdgcn_readlane((int)x, 7);
}

// ---------- feature transpose (B,32,N) -> (B,N,32) ----------
__global__ __launch_bounds__(256) void featT_kernel(const float* __restrict__ feats,
                                                    float* __restrict__ featT) {
  const int bn = blockIdx.x;
  const int b = bn >> 8;
  const int n0 = (bn & 255) * 32;
  __shared__ float tile[32][33];
  const int tx = threadIdx.x & 31, ty = threadIdx.x >> 5;
  const float* src = feats + (size_t)b * 32 * NPTS;
#pragma unroll
  for (int s = 0; s < 4; ++s) {
    int f = ty + 8 * s;
    tile[f][tx] = src[(size_t)f * NPTS + n0 + tx];
  }
  __syncthreads();
  float* dst = featT + ((size_t)b * NPTS + n0) * 32;
#pragma unroll
  for (int s = 0; s < 4; ++s) {
    int n = ty + 8 * s;
    dst[n * 32 + tx] = tile[tx][n];
  }
}

// ---------- weight transpose ----------
__global__ __launch_bounds__(256) void prep_kernel(const float* __restrict__ W1,
                                                   const float* __restrict__ W2,
                                                   const float* __restrict__ W3,
                                                   float* __restrict__ Wt) {
  const int t = blockIdx.x * 256 + threadIdx.x;
  if (t < 2240) { int c = t >> 6, o = t & 63;  Wt[t] = W1[o * 35 + c]; }
  if (t < 4096) { int c = t >> 6, o = t & 63;  Wt[2240 + t] = W2[o * 64 + c]; }
  if (t < 8192) { int c = t >> 7, o = t & 127; Wt[6336 + t] = W3[o * 64 + c]; }
}

// ---------- furthest point sampling (with fused in-LDS counting sort) ----------
// Prologue: counting sort by x-bucket (512 buckets) scattered DIRECTLY into LDS
// lC4[], with the ORIGINAL index packed into .w as int bits (sort is only a
// permutation; all selection is keyed on (dist, ORIGINAL idx)). Main loop is
// byte-for-byte R12: blocked ownership (thread t owns slots [16t,16t+16)),
// exact bbox cull, packed hot loop (fp contract off == bit-exact vs reference),
// two-phase foldable u32 DPP reduces -> exact (max dist, min ORIG idx)
// == jnp.argmax first occurrence. No global memory ops in the loop.
__global__ __launch_bounds__(512) void fps_kernel(const float* __restrict__ coords,
                                                  int* __restrict__ cidx,
                                                  float* __restrict__ centers) {
  const int b = blockIdx.x;
  const int tid = threadIdx.x;
  const int wave = tid >> 6, lane = tid & 63;
  __shared__ __align__(16) float4 lC4[NPTS];  // 128 KiB (w = orig idx bits)
  __shared__ __align__(16) unsigned long long skey[2][8];
  __shared__ int h[512];
  __shared__ int cur[512];
  __shared__ int s_slot0;
  const float* C = coords + (size_t)b * 3 * NPTS;
  // --- histogram ---
  h[tid] = 0;
  __syncthreads();
  int bk[16];
#pragma unroll
  for (int j = 0; j < 16; ++j) {
    const int i = tid + j * 512;
    const float x = C[i];
    int k = (int)(x * 512.0f);
    k = k < 0 ? 0 : (k > 511 ? 511 : k);
    bk[j] = k;
    atomicAdd(&h[k], 1);
  }
  __syncthreads();
  // --- Hillis-Steele inclusive scan over h ---
  const int cnt = h[tid];
  for (int s = 1; s < 512; s <<= 1) {
    int v = (tid >= s) ? h[tid - s] : 0;
    __syncthreads();
    h[tid] += v;
    __syncthreads();
  }
  cur[tid] = h[tid] - cnt;  // exclusive start of bucket tid
  __syncthreads();
  // --- scatter into LDS (within-bucket order nondeterministic; harmless) ---
#pragma unroll
  for (int j = 0; j < 16; ++j) {
    const int i = tid + j * 512;
    const int pos = atomicAdd(&cur[bk[j]], 1);
    float4 v;
    v.x = C[i];
    v.y = C[NPTS + i];
    v.z = C[2 * NPTS + i];
    v.w = __int_as_float(i);  // ORIGINAL index, bit-stashed
    lC4[pos] = v;
  }
  __syncthreads();
  // --- blocked read of owned slots ---
  const int base = tid * 16;
  int og[16];
  v2f px[8], py[8], pz[8], dd[8];
#pragma unroll
  for (int p = 0; p < 8; ++p) {
    float4 c0 = lC4[base + 2 * p];
    float4 c1 = lC4[base + 2 * p + 1];
    px[p].x = c0.x; px[p].y = c1.x;
    py[p].x = c0.y; py[p].y = c1.y;
    pz[p].x = c0.z; pz[p].y = c1.z;
    og[2 * p] = __float_as_int(c0.w);
    og[2 * p + 1] = __float_as_int(c1.w);
    dd[p].x = __builtin_inff(); dd[p].y = __builtin_inff();
  }
#pragma unroll
  for (int j = 0; j < 16; ++j)
    if (og[j] == 0) s_slot0 = base + j;  // exactly one thread writes
  // exact bbox of owned points
  v2f xl = px[0], xh = px[0], yl = py[0], yh = py[0], zl = pz[0], zh = pz[0];
#pragma unroll
  for (int p = 1; p < 8; ++p) {
    xl = __builtin_elementwise_min(xl, px[p]); xh = __builtin_elementwise_max(xh, px[p]);
    yl = __builtin_elementwise_min(yl, py[p]); yh = __builtin_elementwise_max(yh, py[p]);
    zl = __builtin_elementwise_min(zl, pz[p]); zh = __builtin_elementwise_max(zh, pz[p]);
  }
  const float xlo = fminf(xl.x, xl.y), xhi = fmaxf(xh.x, xh.y);
  const float ylo = fminf(yl.x, yl.y), yhi = fmaxf(yh.x, yh.y);
  const float zlo = fminf(zl.x, zl.y), zhi = fmaxf(zh.x, zh.y);
  __syncthreads();
  float cmax = __builtin_inff();
  int amin17 = (og[0] << 4) | 0;
#pragma unroll
  for (int j = 1; j < 16; ++j) amin17 = min(amin17, (og[j] << 4) | j);
  const int slot0 = s_slot0;
  float4 cc = lC4[slot0];
  float cx = cc.x, cy = cc.y, cz = cc.z;
  unsigned long long wkey = 0;
  unsigned long long kreg[4];
  if (tid == 0)  // m=0: initial point, orig 0 (dist bits unused by writeback)
    kreg[0] = ((unsigned long long)(unsigned)8191 << 13) | (unsigned)slot0;
  int buf = 0;
  for (int it = 0; it < MCTR; ++it) {
    float dxm = fmaxf(fmaxf(xlo - cx, cx - xhi), 0.0f);
    float dym = fmaxf(fmaxf(ylo - cy, cy - yhi), 0.0f);
    float dzm = fmaxf(fmaxf(zlo - cz, cz - zhi), 0.0f);
    float lb = dxm * dxm + dym * dym + dzm * dzm;
    bool active = !(lb * 0.999999f >= cmax);  // margin makes skip provably exact
    unsigned long long mk = __ballot(active ? 1 : 0);
    if (mk != 0ull) {
      if (active) {
        v2f vcx, vcy, vcz;
        vcx.x = cx; vcx.y = cx;
        vcy.x = cy; vcy.y = cy;
        vcz.x = cz; vcz.y = cz;
        {
#pragma clang fp contract(off)
          // EXACT reference order per half: (dx*dx + dy*dy) + dz*dz, rn each
          // step, no FMA (contract off). Packed == scalar bit-exact.
#pragma unroll
          for (int p = 0; p < 8; ++p) {
            v2f dx = px[p] - vcx;
            v2f dy = py[p] - vcy;
            v2f dz = pz[p] - vcz;
            v2f d = (dx * dx + dy * dy) + dz * dz;
            dd[p] = __builtin_elementwise_min(dd[p], d);
          }
        }
        v2f m01 = __builtin_elementwise_max(dd[0], dd[1]);
        v2f m23 = __builtin_elementwise_max(dd[2], dd[3]);
        v2f m45 = __builtin_elementwise_max(dd[4], dd[5]);
        v2f m67 = __builtin_elementwise_max(dd[6], dd[7]);
        v2f m03 = __builtin_elementwise_max(m01, m23);
        v2f m47 = __builtin_elementwise_max(m45, m67);
        v2f mm = __builtin_elementwise_max(m03, m47);
        cmax = fmaxf(mm.x, mm.y);
        // min ORIGINAL idx among achievers — depth-4 tree
        int c0, c1, c2, c3, c4, c5, c6, c7;
        c0 = min(dd[0].x == cmax ? ((og[0] << 4) | 0) : 0x7fffffff,
                 dd[0].y == cmax ? ((og[1] << 4) | 1) : 0x7fffffff);
        c1 = min(dd[1].x == cmax ? ((og[2] << 4) | 2) : 0x7fffffff,
                 dd[1].y == cmax ? ((og[3] << 4) | 3) : 0x7fffffff);
        c2 = min(dd[2].x == cmax ? ((og[4] << 4) | 4) : 0x7fffffff,
                 dd[2].y == cmax ? ((og[5] << 4) | 5) : 0x7fffffff);
        c3 = min(dd[3].x == cmax ? ((og[6] << 4) | 6) : 0x7fffffff,
                 dd[3].y == cmax ? ((og[7] << 4) | 7) : 0x7fffffff);
        c4 = min(dd[4].x == cmax ? ((og[8] << 4) | 8) : 0x7fffffff,
                 dd[4].y == cmax ? ((og[9] << 4) | 9) : 0x7fffffff);
        c5 = min(dd[5].x == cmax ? ((og[10] << 4) | 10) : 0x7fffffff,
                 dd[5].y == cmax ? ((og[11] << 4) | 11) : 0x7fffffff);
        c6 = min(dd[6].x == cmax ? ((og[12] << 4) | 12) : 0x7fffffff,
                 dd[6].y == cmax ? ((og[13] << 4) | 13) : 0x7fffffff);
        c7 = min(dd[7].x == cmax ? ((og[14] << 4) | 14) : 0x7fffffff,
                 dd[7].y == cmax ? ((og[15] << 4) | 15) : 0x7fffffff);
        amin17 = min(min(min(c0, c1), min(c2, c3)), min(min(c4, c5), min(c6, c7)));
      }
      const unsigned mydist = __float_as_uint(cmax);
      const unsigned mytail =
          ((unsigned)(8191 - (amin17 >> 4)) << 13) | (unsigned)(base + (amin17 & 15));
      const unsigned gwd = wave_max_u32(mydist);                     // phase A
      const unsigned gwt = wave_max_u32(mydist == gwd ? mytail : 0u);  // phase B
      wkey = ((unsigned long long)gwd << 32) | gwt;
      if (lane == 0) skey[buf][wave] = wkey;
    } else {
      if (lane == 0) skey[buf][wave] = wkey;  // nothing changed in this wave
    }
    __syncthreads();
    // cross-wave: 1 multicast b64 read + two 3-step foldable DPP reduces
    const unsigned long long kc = skey[buf][lane & 7];
    const unsigned kd = (unsigned)(kc >> 32), kt = (unsigned)kc;
    const unsigned gd = oct_max_u32(kd);
    const unsigned gt = oct_max_u32(kd == gd ? kt : 0u);
    const unsigned long long gk = ((unsigned long long)gd << 32) | gt;
    if (((it + 1) >> 2) == tid) kreg[(it + 1) & 3] = gk;  // winner for m=it+1
    const int slot = (int)(gt & 0x1fff);
    float4 c2 = lC4[slot];  // ONE ds_read_b128, wave-uniform broadcast
    cx = c2.x; cy = c2.y; cz = c2.z;
    buf ^= 1;
  }
  // coalesced writeback: thread t owns centers m = 4t..4t+3
#pragma unroll
  for (int r = 0; r < 4; ++r) {
    unsigned long long k = kreg[r];
    int orig = 8191 - (int)((k >> 13) & 0x1fff);
    int sl = (int)(k & 0x1fff);
    int m = 4 * tid + r;
    float4 c = lC4[sl];
    cidx[b * MCTR + m] = orig;
    centers[(size_t)b * 3 * MCTR + m] = c.x;
    centers[(size_t)b * 3 * MCTR + MCTR + m] = c.y;
    centers[(size_t)b * 3 * MCTR + 2 * MCTR + m] = c.z;
  }
}

// ---------- ball query: one wave per center, software-pipelined loads ----------
__global__ __launch_bounds__(256) void ballq_kernel(const float* __restrict__ coords,
                                                    const int* __restrict__ cidx,
                                                    int* __restrict__ nbidx) {
  const int wib = threadIdx.x >> 6;
  const int gw = blockIdx.x * 4 + wib;
  const int lane = threadIdx.x & 63;
  const int b = gw >> 11;
  const float* C = coords + (size_t)b * 3 * NPTS;
  const int ci = cidx[gw];
  const float cx = C[ci], cy = C[NPTS + ci], cz = C[2 * NPTS + ci];
  // python double 0.2*0.2 demoted to f32 == 0x3D23D70A (NOT 0.2f*0.2f!)
  const float R2 = (float)(0.2 * 0.2);
  __shared__ int sbuf[4][32];
  int* buf = sbuf[wib];
  int count = 0;
  float xx = C[lane], yy = C[NPTS + lane], zz = C[2 * NPTS + lane];
  for (int base = 0; base < NPTS && count < 32; base += 64) {
    float nx = 0.f, ny = 0.f, nz = 0.f;
    if (base + 64 < NPTS) {  // prefetch next round while this round resolves
      const int ni = base + 64 + lane;
      nx = C[ni]; ny = C[NPTS + ni]; nz = C[2 * NPTS + ni];
    }
    float dx = __fsub_rn(cx, xx);
    float dy = __fsub_rn(cy, yy);
    float dz = __fsub_rn(cz, zz);
    float d2 = __fadd_rn(__fadd_rn(__fmul_rn(dx, dx), __fmul_rn(dy, dy)), __fmul_rn(dz, dz));
    bool q = d2 < R2;
    unsigned long long mk = __ballot(q ? 1 : 0);
    int pos = count + (int)__popcll(mk & ((1ull << lane) - 1ull));
    if (q && pos < 32) buf[pos] = base + lane;
    count += (int)__popcll(mk);
    xx = nx; yy = ny; zz = nz;
  }
  __syncthreads();
  if (lane < 32) {
    int cnt = count < 32 ? count : 32;
    int first = (count > 0) ? buf[0] : 0;
    int v = (lane < cnt) ? buf[lane] : first;
    nbidx[(size_t)gw * KNB + lane] = v;
  }
}

// ---------- MLP with XOR-swizzled LDS ----------
__device__ __forceinline__ int SW(int ch, int col) {
  return 32 * ch + (col ^ ((((ch) >> 2) & 7) << 2));
}

__device__ __forceinline__ void layerT(const float* __restrict__ X,
                                       const float* __restrict__ W, int ldw, int cin,
                                       float4 bias, int og, int kg, float acc[4][8]) {
  const float bv[4] = {bias.x, bias.y, bias.z, bias.w};
#pragma unroll
  for (int oi = 0; oi < 4; ++oi)
#pragma unroll
    for (int ki = 0; ki < 8; ++ki) acc[oi][ki] = bv[oi];
#pragma unroll 4
  for (int c = 0; c < cin; ++c) {
    const float4 xa = *(const float4*)(X + SW(c, 8 * kg));
    const float4 xb = *(const float4*)(X + SW(c, 8 * kg + 4));
    float4 w = *(const float4*)(W + ldw * c + 4 * og);
    const float wv[4] = {w.x, w.y, w.z, w.w};
    const float xv[8] = {xa.x, xa.y, xa.z, xa.w, xb.x, xb.y, xb.z, xb.w};
#pragma unroll
    for (int oi = 0; oi < 4; ++oi)
#pragma unroll
      for (int ki = 0; ki < 8; ++ki)
        acc[oi][ki] = fmaf(wv[oi], xv[ki], acc[oi][ki]);
  }
}

__device__ __forceinline__ void storeT(float* __restrict__ dst, int og, int kg,
                                       const float acc[4][8]) {
#pragma unroll
  for (int oi = 0; oi < 4; ++oi) {
    float4 va, vb;
    va.x = fmaxf(acc[oi][0], 0.f); va.y = fmaxf(acc[oi][1], 0.f);
    va.z = fmaxf(acc[oi][2], 0.f); va.w = fmaxf(acc[oi][3], 0.f);
    vb.x = fmaxf(acc[oi][4], 0.f); vb.y = fmaxf(acc[oi][5], 0.f);
    vb.z = fmaxf(acc[oi][6], 0.f); vb.w = fmaxf(acc[oi][7], 0.f);
    const int r = 4 * og + oi;
    *(float4*)(dst + SW(r, 8 * kg)) = va;
    *(float4*)(dst + SW(r, 8 * kg + 4)) = vb;
  }
}

__global__ __launch_bounds__(64) void mlp_kernel(const float* __restrict__ coords,
                                                 const float* __restrict__ featT,
                                                 const float* __restrict__ Wt,
                                                 const float* __restrict__ b1,
                                                 const float* __restrict__ b2,
                                                 const float* __restrict__ b3,
                                                 const int* __restrict__ cidx,
                                                 const int* __restrict__ nbidx,
                                                 float* __restrict__ outT) {
  const int g = blockIdx.x;
  const int b = g >> 11;
  const int lane = threadIdx.x;
  const int og = lane & 15, kg = lane >> 4;
  __shared__ __align__(16) float A[64 * 32];
  __shared__ __align__(16) float Bf[64 * 32];
  const float* C = coords + (size_t)b * 3 * NPTS;
  const int ci = cidx[g];
  const float ccx = C[ci], ccy = C[NPTS + ci], ccz = C[2 * NPTS + ci];
  const int* nb = nbidx + (size_t)g * KNB;
  if (lane < 32) {
    const int n = nb[lane];
    A[SW(0, lane)] = C[n] - ccx;
    A[SW(1, lane)] = C[NPTS + n] - ccy;
    A[SW(2, lane)] = C[2 * NPTS + n] - ccz;
    const float4* f = (const float4*)(featT + ((size_t)b * NPTS + n) * 32);
#pragma unroll
    for (int q = 0; q < 4; ++q) {
      float4 v = f[q];
      A[SW(3 + 4 * q, lane)] = v.x;
      A[SW(4 + 4 * q, lane)] = v.y;
      A[SW(5 + 4 * q, lane)] = v.z;
      A[SW(6 + 4 * q, lane)] = v.w;
    }
  } else {
    const int k = lane - 32;
    const int n = nb[k];
    const float4* f = (const float4*)(featT + ((size_t)b * NPTS + n) * 32);
#pragma unroll
    for (int q = 4; q < 8; ++q) {
      float4 v = f[q];
      A[SW(3 + 4 * q, k)] = v.x;
      A[SW(4 + 4 * q, k)] = v.y;
      A[SW(5 + 4 * q, k)] = v.z;
      A[SW(6 + 4 * q, k)] = v.w;
    }
  }
  __syncthreads();
  float acc[4][8];
  layerT(A, Wt, 64, 35, *(const float4*)(b1 + 4 * og), og, kg, acc);
  storeT(Bf, og, kg, acc);
  __syncthreads();
  layerT(Bf, Wt + 2240, 64, 64, *(const float4*)(b2 + 4 * og), og, kg, acc);
  storeT(A, og, kg, acc);
  __syncthreads();
  float* outp = outT + (size_t)g * 128;
#pragma unroll 1
  for (int h = 0; h < 2; ++h) {
    layerT(A, Wt + 6336 + 64 * h, 128, 64, *(const float4*)(b3 + 64 * h + 4 * og), og,
           kg, acc);
    float4 res;
    float* rp = (float*)&res;
#pragma unroll
    for (int oi = 0; oi < 4; ++oi) {
      float m = 0.f;
#pragma unroll
      for (int ki = 0; ki < 8; ++ki) m = fmaxf(m, acc[oi][ki]);
      m = fmaxf(m, __shfl_xor(m, 16));
      m = fmaxf(m, __shfl_xor(m, 32));
      rp[oi] = m;
    }
    if (kg == 0) *(float4*)(outp + 64 * h + 4 * og) = res;
  }
}

// ---------- output transpose (B,M,128) -> (B,128,M) ----------
__global__ __launch_bounds__(256) void outT_kernel(const float* __restrict__ outT,
                                                   float* __restrict__ out) {
  const int bid = blockIdx.x;
  const int b = bid >> 8;
  const int r = bid & 255;
  const int o0 = (r >> 6) * 32;
  const int m0 = (r & 63) * 32;
  __shared__ float tile[32][33];
  const int tx = threadIdx.x & 31, ty = threadIdx.x >> 5;
  const float* src = outT + ((size_t)b * MCTR + m0) * 128;
#pragma unroll
  for (int s = 0; s < 4; ++s) {
    int m = ty + 8 * s;
    tile[m][tx] = src[(size_t)m * 128 + o0 + tx];
  }
  __syncthreads();
  float* dst = out + ((size_t)b * 128 + o0) * MCTR + m0;
#pragma unroll
  for (int s = 0; s < 4; ++s) {
    int o = ty + 8 * s;
    dst[(size_t)o * MCTR + tx] = tile[tx][o];
  }
}

extern "C" void kernel_launch(void* const* d_in, const int* in_sizes, int n_in,
                              void* d_out, int out_size, void* d_ws, size_t ws_size,
                              hipStream_t stream) {
  (void)in_sizes; (void)n_in; (void)out_size; (void)ws_size;
  const float* feats = (const float*)d_in[0];
  const float* coords = (const float*)d_in[1];
  const float* W1 = (const float*)d_in[2];
  const float* b1 = (const float*)d_in[3];
  const float* W2 = (const float*)d_in[4];
  const float* b2 = (const float*)d_in[5];
  const float* W3 = (const float*)d_in[6];
  const float* b3 = (const float*)d_in[7];
  float* out = (float*)d_out;
  float* centers = out + (size_t)BATCH * 128 * MCTR;

  float* ws_f = (float*)d_ws;
  float* featT = ws_f;                                     // 1,048,576 f
  float* Wt = ws_f + 1048576;                              //    14,528 f
  int* cidx = (int*)(ws_f + 1048576 + 14528);              //     8,192 i
  int* nbidx = (int*)(ws_f + 1048576 + 14528 + 8192);      //   262,144 i
  float* outTbuf = ws_f + 1048576 + 14528 + 8192 + 262144; // 1,048,576 f

  featT_kernel<<<1024, 256, 0, stream>>>(feats, featT);
  prep_kernel<<<32, 256, 0, stream>>>(W1, W2, W3, Wt);
  fps_kernel<<<BATCH, 512, 0, stream>>>(coords, cidx, centers);
  ballq_kernel<<<2048, 256, 0, stream>>>(coords, cidx, nbidx);
  mlp_kernel<<<BATCH * MCTR, 64, 0, stream>>>(coords, featT, Wt, b1, b2, b3, cidx, nbidx, outTbuf);
  outT_kernel<<<1024, 256, 0, stream>>>(outTbuf, out);
}